// Round 10
// baseline (111.216 us; speedup 1.0000x reference)
//
#include <hip/hip_runtime.h>

// Single-head causal attention. Round 10: R9 with the dead-code compile
// error removed. Row-split waves; x streamed global->register (lane-private,
// 2 chunks ahead, no LDS, no barriers); only wt (L2-resident) goes through a
// barrier-guarded LDS double buffer.
// B=2048, T=64, C=768, H=64. Inputs fp32: x, Wk, Wq, Wv ([in,out] layout).

#define BATCHES 2048
#define SEQ 64
#define CDIM 768
#define HDIM 64
#define NCX 24  // 768 / 32

typedef __bf16 bf16x8 __attribute__((ext_vector_type(8)));
typedef float f32x4v __attribute__((ext_vector_type(4)));
typedef unsigned short u16x8 __attribute__((ext_vector_type(8)));

__device__ __forceinline__ unsigned short f2bf(float f) {
  return __builtin_bit_cast(unsigned short, (__bf16)f);
}

// XOR swizzle for 64-elem bf16 parking rows: elem col ^= ((row&7)<<3)
__device__ __forceinline__ int swz(int row, int col) {
  return row * 64 + (col ^ ((row & 7) << 3));
}

__device__ __forceinline__ f32x4v mfma16(bf16x8 a, bf16x8 b, f32x4v c) {
  return __builtin_amdgcn_mfma_f32_16x16x32_bf16(a, b, c, 0, 0, 0);
}

__device__ __forceinline__ bf16x8 lds_frag(const unsigned short* p, int row, int col) {
  return __builtin_bit_cast(bf16x8, *reinterpret_cast<const u16x8*>(p + swz(row, col)));
}

__device__ __forceinline__ void gl_lds16(const void* g, void* l) {
  __builtin_amdgcn_global_load_lds(
      (const __attribute__((address_space(1))) void*)g,
      (__attribute__((address_space(3))) void*)l, 16, 0, 0);
}

// Prep (verified R4/R5/R7): chunk stride 12288 B, slots 0..767.
// ws element i: c = i/6144, slot = (i%6144)>>3, e = i&7;
// row = slot>>2 (mat*64+h), p = slot&3, g = p^((row>>1)&3), k = c*32+g*8+e.
__global__ __launch_bounds__(256) void prep_wt_kernel(
    const float* __restrict__ Wk, const float* __restrict__ Wq,
    const float* __restrict__ Wv, unsigned short* __restrict__ wt) {
  int i = blockIdx.x * 256 + threadIdx.x;
  if (i >= 3 * HDIM * CDIM) return;
  int c = i / 6144;
  int r2 = i - c * 6144;
  int slot = r2 >> 3;
  int e = r2 & 7;
  int row = slot >> 2;
  int p = slot & 3;
  int g = p ^ ((row >> 1) & 3);
  int k = c * 32 + g * 8 + e;
  int mat = row >> 6;
  int h = row & 63;
  const float* W = (mat == 0) ? Wq : ((mat == 1) ? Wk : Wv);
  wt[i] = f2bf(W[k * HDIM + h]);
}

__global__ __launch_bounds__(512, 2) void head_fused_kernel(
    const float* __restrict__ x, const unsigned short* __restrict__ wt,
    float* __restrict__ out) {
  const int bid = blockIdx.x;        // batches 2*bid, 2*bid+1
  const int tid = threadIdx.x;
  const int w = tid >> 6;            // wave 0..7
  const int ww = w & 3;              // rows [16ww, 16ww+16)
  const int bat = w >> 2;            // 0/1 -> batch 2*bid+bat
  const int lane = tid & 63;
  const int lane15 = lane & 15;
  const int lhi = lane >> 4;

  // LDS 48 KB: wt dbuf [wb0 12K @0][wb1 12K @12K] during streaming;
  // parking (after final barrier) aliases: region bat*24576: [k|vT|qp] 8K each.
  __shared__ __align__(16) unsigned char smem[49152];

  // ---- wt staging (R5-verified layout; dest = wave-uniform + lane*16) ------
  // W chunk = 12 regions x 1KB (64 lanes x 16B). Wave w DMAs region w;
  // waves 0..3 additionally DMA region 8+w.
  const char* wbaseA = (const char*)wt + (w * 64 + lane) * 16;
  const char* wbase2 = (const char*)wt + (((8 + w) * 64 + lane)) * 16;
  const int wdstA = (w * 64 + lane) * 16;
  const int wdst2 = ((8 + w) * 64 + lane) * 16;

  #define STAGE_WT(cn, B)                                                   \
    do {                                                                    \
      char* wbp = (char*)smem + (B) * 12288;                                \
      gl_lds16(wbaseA + (cn) * 12288, wbp + wdstA);                         \
      if (w < 4) gl_lds16(wbase2 + (cn) * 12288, wbp + wdst2);              \
    } while (0)

  // ---- x per-lane direct stream --------------------------------------------
  const char* xlane = (const char*)x + (size_t)(2 * bid + bat) * 196608 +
                      (16 * ww + lane15) * 3072 + lhi * 32;
  #define ISSUE_X(cn, D0, D1)                                               \
    do {                                                                    \
      D0 = *reinterpret_cast<const f32x4v*>(xlane + (cn) * 128);            \
      D1 = *reinterpret_cast<const f32x4v*>(xlane + (cn) * 128 + 16);       \
    } while (0)

  const f32x4v z4 = {0.f, 0.f, 0.f, 0.f};
  f32x4v accq[4], acck[4], accv[4];
  #pragma unroll
  for (int n = 0; n < 4; ++n) { accq[n] = z4; acck[n] = z4; accv[n] = z4; }

  #define COMPUTE(c, X0, X1)                                                \
    do {                                                                    \
      const unsigned short* ws =                                            \
          (const unsigned short*)((char*)smem + ((c) & 1) * 12288);         \
      u16x8 ar;                                                             \
      _Pragma("unroll")                                                     \
      for (int i = 0; i < 4; ++i) { ar[i] = f2bf(X0[i]); ar[4 + i] = f2bf(X1[i]); } \
      bf16x8 a = __builtin_bit_cast(bf16x8, ar);                            \
      _Pragma("unroll")                                                     \
      for (int n = 0; n < 4; ++n) {                                         \
        int brq = 0 * HDIM + 16 * n + lane15;                               \
        int bpq = lhi ^ ((brq >> 1) & 3);                                   \
        bf16x8 bq = __builtin_bit_cast(bf16x8,                              \
            *reinterpret_cast<const u16x8*>(ws + brq * 32 + bpq * 8));      \
        accq[n] = mfma16(a, bq, accq[n]);                                   \
        int brk = 1 * HDIM + 16 * n + lane15;                               \
        int bpk = lhi ^ ((brk >> 1) & 3);                                   \
        bf16x8 bk = __builtin_bit_cast(bf16x8,                              \
            *reinterpret_cast<const u16x8*>(ws + brk * 32 + bpk * 8));      \
        acck[n] = mfma16(a, bk, acck[n]);                                   \
        int brv = 2 * HDIM + 16 * n + lane15;                               \
        int bpv = lhi ^ ((brv >> 1) & 3);                                   \
        bf16x8 bv = __builtin_bit_cast(bf16x8,                              \
            *reinterpret_cast<const u16x8*>(ws + brv * 32 + bpv * 8));      \
        accv[n] = mfma16(a, bv, accv[n]);                                   \
      }                                                                     \
    } while (0)

  // Per-wave vm queue at ITER(c) entry: wt(c)[W], x(c)[2], wt(c+1)[W], x(c+1)[2]
  // (W = 2 for waves 0-3, 1 for waves 4-7). Wait through x(c): leave W+2.
  #define ITER(c, X0, X1)                                                   \
    do {                                                                    \
      if ((c) < NCX - 1) {                                                  \
        if (w < 4) asm volatile("s_waitcnt vmcnt(4)" ::: "memory");         \
        else       asm volatile("s_waitcnt vmcnt(3)" ::: "memory");         \
      } else {                                                              \
        asm volatile("s_waitcnt vmcnt(0)" ::: "memory");                    \
      }                                                                     \
      __builtin_amdgcn_sched_barrier(0);                                    \
      __builtin_amdgcn_s_barrier();                                         \
      COMPUTE(c, X0, X1);                                                   \
      asm volatile("s_waitcnt lgkmcnt(0)" ::: "memory");                    \
      __builtin_amdgcn_sched_barrier(0);                                    \
      __builtin_amdgcn_s_barrier();                                         \
      if ((c) + 2 < NCX) {                                                  \
        STAGE_WT((c) + 2, (c) & 1);                                         \
        __builtin_amdgcn_sched_barrier(0);                                  \
        ISSUE_X((c) + 2, X0, X1);                                           \
        __builtin_amdgcn_sched_barrier(0);                                  \
      }                                                                     \
    } while (0)

  f32x4v PA0, PA1, PB0, PB1;

  // prologue: queue = wt0[W], x0[2], wt1[W], x1[2]
  STAGE_WT(0, 0);
  __builtin_amdgcn_sched_barrier(0);
  ISSUE_X(0, PA0, PA1);
  __builtin_amdgcn_sched_barrier(0);
  STAGE_WT(1, 1);
  __builtin_amdgcn_sched_barrier(0);
  ISSUE_X(1, PB0, PB1);
  __builtin_amdgcn_sched_barrier(0);

  ITER(0, PA0, PA1);   ITER(1, PB0, PB1);
  ITER(2, PA0, PA1);   ITER(3, PB0, PB1);
  ITER(4, PA0, PA1);   ITER(5, PB0, PB1);
  ITER(6, PA0, PA1);   ITER(7, PB0, PB1);
  ITER(8, PA0, PA1);   ITER(9, PB0, PB1);
  ITER(10, PA0, PA1);  ITER(11, PB0, PB1);
  ITER(12, PA0, PA1);  ITER(13, PB0, PB1);
  ITER(14, PA0, PA1);  ITER(15, PB0, PB1);
  ITER(16, PA0, PA1);  ITER(17, PB0, PB1);
  ITER(18, PA0, PA1);  ITER(19, PB0, PB1);
  ITER(20, PA0, PA1);  ITER(21, PB0, PB1);
  ITER(22, PA0, PA1);  ITER(23, PB0, PB1);

  #undef ITER
  #undef COMPUTE
  #undef ISSUE_X
  #undef STAGE_WT

  // ---- epilogue (R5-verified): parking + phases 2-5, one round --------------
  unsigned short* k_lds  = (unsigned short*)((char*)smem + bat * 24576);
  unsigned short* vT_lds = (unsigned short*)((char*)smem + bat * 24576 + 8192);
  unsigned short* qp_lds = (unsigned short*)((char*)smem + bat * 24576 + 16384);

  // C/D layout: col = lane&15, row = (lane>>4)*4 + j   [measured m89/m91]
  #pragma unroll
  for (int n = 0; n < 4; ++n) {
    int h = 16 * n + lane15;
    #pragma unroll
    for (int j = 0; j < 4; ++j) {
      int s = 16 * ww + lhi * 4 + j;
      k_lds[swz(s, h)] = f2bf(acck[n][j]);
      vT_lds[swz(h, s)] = f2bf(accv[n][j]);
      qp_lds[swz(s, h)] = f2bf(accq[n][j]);
    }
  }
  __syncthreads();

  // phase 2: S = q k^T
  const int trow = 16 * ww + lane15;
  bf16x8 aq0 = lds_frag(qp_lds, trow, lhi * 8);
  bf16x8 aq1 = lds_frag(qp_lds, trow, 32 + lhi * 8);
  f32x4v accS[4];
  #pragma unroll
  for (int n = 0; n < 4; ++n) accS[n] = z4;
  #pragma unroll
  for (int sB = 0; sB < 4; ++sB) {
    if (sB <= ww) {  // causal: col blocks above the diagonal are all-masked
      bf16x8 bk0 = lds_frag(k_lds, 16 * sB + lane15, lhi * 8);
      bf16x8 bk1 = lds_frag(k_lds, 16 * sB + lane15, 32 + lhi * 8);
      accS[sB] = mfma16(aq0, bk0, accS[sB]);
      accS[sB] = mfma16(aq1, bk1, accS[sB]);
    }
  }

  // phase 3: fp32 causal softmax, P -> bf16 LDS
  float rinv[4];
  #pragma unroll
  for (int j = 0; j < 4; ++j) {
    int t = 16 * ww + lhi * 4 + j;
    float zv[4];
    float m = -3.0e38f;
    #pragma unroll
    for (int sB = 0; sB < 4; ++sB) {
      int sc = 16 * sB + lane15;
      float zz = (sB <= ww && sc <= t) ? accS[sB][j] * 0.125f : -3.0e38f;
      zv[sB] = zz;
      m = fmaxf(m, zz);
    }
    #pragma unroll
    for (int off = 1; off < 16; off <<= 1) m = fmaxf(m, __shfl_xor(m, off));
    float sum = 0.f;
    float pv[4];
    #pragma unroll
    for (int sB = 0; sB < 4; ++sB) {
      float pe = __expf(zv[sB] - m);  // masked -> exp(-huge) = 0
      pv[sB] = pe;
      sum += pe;
    }
    #pragma unroll
    for (int off = 1; off < 16; off <<= 1) sum += __shfl_xor(sum, off);
    rinv[j] = 1.0f / sum;
    #pragma unroll
    for (int sB = 0; sB < 4; ++sB)
      qp_lds[swz(t, 16 * sB + lane15)] = f2bf(pv[sB]);
  }
  __syncthreads();  // P visible before A-frag reads

  // phase 4: O = P V
  f32x4v accO[4];
  #pragma unroll
  for (int n = 0; n < 4; ++n) accO[n] = z4;
  #pragma unroll
  for (int s0 = 0; s0 < 64; s0 += 32) {
    if (s0 <= 16 * ww + 15) {  // causal: later s-blocks all zero for this wave
      bf16x8 ap = lds_frag(qp_lds, trow, s0 + lhi * 8);
      #pragma unroll
      for (int n = 0; n < 4; ++n) {
        bf16x8 bv = lds_frag(vT_lds, 16 * n + lane15, s0 + lhi * 8);
        accO[n] = mfma16(ap, bv, accO[n]);
      }
    }
  }

  // phase 5: normalize + store fp32
  float* op = out + (size_t)(2 * bid + bat) * (SEQ * HDIM);
  #pragma unroll
  for (int n = 0; n < 4; ++n) {
    int h = 16 * n + lane15;
    #pragma unroll
    for (int j = 0; j < 4; ++j) {
      int t = 16 * ww + lhi * 4 + j;
      op[t * HDIM + h] = accO[n][j] * rinv[j];
    }
  }
}

extern "C" void kernel_launch(void* const* d_in, const int* in_sizes, int n_in,
                              void* d_out, int out_size, void* d_ws, size_t ws_size,
                              hipStream_t stream) {
  const float* x  = (const float*)d_in[0];
  const float* Wk = (const float*)d_in[1];
  const float* Wq = (const float*)d_in[2];
  const float* Wv = (const float*)d_in[3];
  float* out = (float*)d_out;
  unsigned short* wt = (unsigned short*)d_ws;  // 24 chunks x 12 KB = 288 KiB

  hipLaunchKernelGGL(prep_wt_kernel, dim3((3 * HDIM * CDIM + 255) / 256), dim3(256),
                     0, stream, Wk, Wq, Wv, wt);
  hipLaunchKernelGGL(head_fused_kernel, dim3(BATCHES / 2), dim3(512), 0, stream,
                     x, wt, out);
}